// Round 6
// baseline (4665.554 us; speedup 1.0000x reference)
//
#include <hip/hip_runtime.h>

// LSTM S=512,B=64,I=256,H=512 (f32 buffers).
// R6: two paths gated on ws_size.
//  XP path (ws >= ~138 MB): precompute x-projection XP[grow][t*64+b] (f16)
//   with a 256-WG MFMA GEMM (all CUs), fold biases in. Recurrent loop is then
//   h-GEMM only (K=512): B-fragments loaded DIRECTLY from the coherent hb
//   buffer (16B of hb == one MFMA B-frag), no LDS restage. XP prefetched
//   before the flag spin. R5's proven fence-free relaxed-atomic protocol.
//  Fallback path: R5 kernel verbatim (proven 2.63 ms).

#define SS 512
#define BB 64
#define II 256
#define HH 512
#define NWG 32
#define GROW 2048            // 4*HH gate rows
#define TBN  (SS*BB)         // 32768

typedef unsigned int u32;
typedef unsigned short u16;
typedef unsigned long long u64;
typedef _Float16 __attribute__((ext_vector_type(8))) h16x8;
typedef __attribute__((ext_vector_type(2))) float f32x2;
typedef __attribute__((ext_vector_type(4))) float f32x4;
typedef __attribute__((ext_vector_type(16))) float f32x16;
typedef u32 __attribute__((ext_vector_type(4))) u32x4;
typedef u32 __attribute__((ext_vector_type(2))) u32x2;

// ---------------- XP-path ws layout ----------------
#define A2_DW   (NWG * 2 * 2 * 16 * 256)      // 524288 dwords = 2 MB (h A-frags)
#define WXA_DW  (64 * 16 * 256)               // 262144 dwords = 1 MB (x A-frags)
#define XA2_OFF  0
#define XWXA_OFF ((size_t)A2_DW * 4)                    // 2,097,152
#define XBS_OFF  (XWXA_OFF + (size_t)WXA_DW * 4)        // 3,145,728 (bsum 8 KB)
#define XHB_OFF  (XBS_OFF + 8192)                       // 3,153,920 (hb 128 KB)
#define XFL_OFF  (XHB_OFF + 2 * (size_t)BB * HH * 2)    // 3,284,992 (flags)
#define XXP_OFF  ((size_t)4 * 1024 * 1024)              // 4,194,304
#define XP_BYTES ((size_t)GROW * TBN * 2)               // 134,217,728
#define WS_XP    (XXP_OFF + XP_BYTES)                   // 138,412,032

// ---------------- R5-path ws layout ----------------
#define A_DWORDS (NWG * 2 * 2 * 24 * 64 * 4)          // 786432
#define HB_OFF   ((size_t)A_DWORDS * 4)               // 3,145,728
#define FL_OFF   (HB_OFF + 2 * (size_t)BB * HH * 2)   // +131,072
#define WS_NEED  (FL_OFF + 4096)

__device__ __forceinline__ u32 pk2h(float a, float b) {
    union { _Float16 h[2]; u32 u; } v;
    v.h[0] = (_Float16)a; v.h[1] = (_Float16)b; return v.u;
}
__device__ __forceinline__ u16 f2h(float a) {
    union { _Float16 h; u16 u; } v; v.h = (_Float16)a; return v.u;
}
__device__ __forceinline__ float h2f(u16 u) {
    union { u16 u; _Float16 h; } v; v.u = u; return (float)v.h;
}
__device__ __forceinline__ float sigf(float v)  { return 1.0f / (1.0f + __expf(-v)); }
__device__ __forceinline__ float tanhf_(float v){ return 1.0f - 2.0f / (1.0f + __expf(2.0f * v)); }

// relaxed agent-scope (coherent-at-L3, no cache-maintenance fences)
__device__ __forceinline__ void st_u32_coh(u32* p, u32 v) {
    __hip_atomic_store(p, v, __ATOMIC_RELAXED, __HIP_MEMORY_SCOPE_AGENT);
}
__device__ __forceinline__ void st_i32_coh(int* p, int v) {
    __hip_atomic_store(p, v, __ATOMIC_RELAXED, __HIP_MEMORY_SCOPE_AGENT);
}
__device__ __forceinline__ int ld_i32_coh(const int* p) {
    return __hip_atomic_load(p, __ATOMIC_RELAXED, __HIP_MEMORY_SCOPE_AGENT);
}
__device__ __forceinline__ u32 ld_u32_coh(const u32* p) {
    return __hip_atomic_load(p, __ATOMIC_RELAXED, __HIP_MEMORY_SCOPE_AGENT);
}
__device__ __forceinline__ u64 ld_u64_coh(const u64* p) {
    return __hip_atomic_load(p, __ATOMIC_RELAXED, __HIP_MEMORY_SCOPE_AGENT);
}

// ===================================================================
// XP path
// ===================================================================

// pack: A2 (h-weights as MFMA A-frags), WXA (x-weights as A-frags for xproj),
// bsum (combined biases per gate-row). grow = wg*64 + g*16 + m, j = wg*16+m.
__global__ __launch_bounds__(256) void xprep_pack(
    const float* __restrict__ Wfi, const float* __restrict__ Wfh,
    const float* __restrict__ Wii, const float* __restrict__ Wih,
    const float* __restrict__ Wci, const float* __restrict__ Wch,
    const float* __restrict__ Woi, const float* __restrict__ Woh,
    const float* __restrict__ bfi, const float* __restrict__ bfh,
    const float* __restrict__ bii, const float* __restrict__ bih,
    const float* __restrict__ bci, const float* __restrict__ bch,
    const float* __restrict__ boi, const float* __restrict__ boh,
    u32* __restrict__ A2, u32* __restrict__ WXA, float* __restrict__ bsum)
{
    int tid = blockIdx.x * 256 + threadIdx.x;
    if (tid < A2_DW) {
        // idx = wg*16384 + mt*8192 + ks*4096 + kt*256 + l*4 + d
        int d = tid & 3, l = (tid >> 2) & 63, kt = (tid >> 8) & 15;
        int ks = (tid >> 12) & 1, mt = (tid >> 13) & 1, wg = tid >> 14;
        int row = mt * 32 + (l & 31);
        int g = row >> 4, j = wg * 16 + (row & 15);
        int k = ks * 256 + kt * 16 + (l >> 5) * 8 + d * 2;
        const float* Wh = (g == 0) ? Wfh : (g == 1) ? Wih : (g == 2) ? Wch : Woh;
        A2[tid] = pk2h(Wh[j * HH + k], Wh[j * HH + k + 1]);
    } else if (tid < A2_DW + WXA_DW) {
        int t2 = tid - A2_DW;
        // idx = gt*4096 + kt*256 + l*4 + d
        int d = t2 & 3, l = (t2 >> 2) & 63, kt = (t2 >> 8) & 15, gt = t2 >> 12;
        int grow = gt * 32 + (l & 31);
        int g = (grow >> 4) & 3, j = (grow >> 6) * 16 + (grow & 15);
        int k = kt * 16 + (l >> 5) * 8 + d * 2;
        const float* Wi = (g == 0) ? Wfi : (g == 1) ? Wii : (g == 2) ? Wci : Woi;
        WXA[t2] = pk2h(Wi[j * II + k], Wi[j * II + k + 1]);
    } else if (tid < A2_DW + WXA_DW + GROW) {
        int grow = tid - A2_DW - WXA_DW;
        int g = (grow >> 4) & 3, j = (grow >> 6) * 16 + (grow & 15);
        const float* bi = (g == 0) ? bfi : (g == 1) ? bii : (g == 2) ? bci : boi;
        const float* bh = (g == 0) ? bfh : (g == 1) ? bih : (g == 2) ? bch : boh;
        bsum[grow] = bi[j] + bh[j];
    }
}

__global__ __launch_bounds__(256) void xprep_hb(
    const float* __restrict__ h0, u16* __restrict__ hb, int* __restrict__ flags)
{
    int tid = blockIdx.x * 256 + threadIdx.x;   // < 32768
    if (tid < BB * HH) {
        int b = tid >> 9, j = tid & 511;
        hb[(j >> 3) * 512 + b * 8 + (j & 7)] = f2h(h0[tid]);
    }
    if (tid < NWG) flags[tid] = 0;
}

// xproj: XP[grow][tb] = sum_k Wx[grow,k]*x[tb,k] + bsum[grow]  (f16 out)
// 256 WGs, each owns 128 tb-rows. M=grow (A=Wx), N=tb (B=x), K=256.
__global__ __launch_bounds__(512, 1) void xproj(
    const float* __restrict__ x, const u32* __restrict__ WXA,
    const float* __restrict__ bsum, u16* __restrict__ XP)
{
    const int wgid = blockIdx.x;
    const int tid = threadIdx.x, lane = tid & 63, w = tid >> 6;
    const int TB0 = wgid * 128;
    __shared__ __align__(16) u32 XB[32 * 128 * 4];   // [k8][tbl] 16B entries

    // stage x-tile (128 tb x 256 k) f32 -> f16 packed
    #pragma unroll
    for (int it = 0; it < 16; ++it) {
        int c = it * 512 + tid;          // 16B-chunk of f32 source
        int m = c >> 6, ck = c & 63;     // k = ck*4
        f32x4 v = *(const f32x4*)(x + (size_t)(TB0 + m) * II + ck * 4);
        u32x2 p; p.x = pk2h(v.x, v.y); p.y = pk2h(v.z, v.w);
        *(u32x2*)(XB + ((ck >> 1) * 128 + m) * 4 + (ck & 1) * 2) = p;
    }
    __syncthreads();

    const int gtw = w & 3, nh = w >> 2;
    const int khi = lane >> 5;
    for (int nt = 0; nt < 2; ++nt) {
        const int col = nh * 64 + nt * 32 + (lane & 31);   // tb-local
        h16x8 bfr[16];
        #pragma unroll
        for (int kt = 0; kt < 16; ++kt)
            bfr[kt] = *(const h16x8*)(XB + ((kt * 2 + khi) * 128 + col) * 4);
        for (int gti = 0; gti < 16; ++gti) {
            const int gt = gtw * 16 + gti;
            f32x16 acc;
            #pragma unroll
            for (int rg = 0; rg < 16; ++rg)
                acc[rg] = bsum[gt * 32 + (rg & 3) + 8 * (rg >> 2) + 4 * khi];
            const u32* ap = WXA + (size_t)(gt * 16) * 256 + lane * 4;
            #pragma unroll
            for (int kt = 0; kt < 16; ++kt) {
                h16x8 af = *(const h16x8*)(ap + kt * 256);
                acc = __builtin_amdgcn_mfma_f32_32x32x16_f16(af, bfr[kt], acc, 0, 0, 0);
            }
            #pragma unroll
            for (int rg = 0; rg < 16; ++rg) {
                int grow = gt * 32 + (rg & 3) + 8 * (rg >> 2) + 4 * khi;
                XP[(size_t)grow * TBN + TB0 + col] = f2h(acc[rg]);
            }
        }
    }
}

// recurrent: h-GEMM only, B-frags direct from hb (coherent), XP in pointwise.
__global__ __launch_bounds__(512, 1) void lstm_rec(
    const float* __restrict__ c0,
    const u32* __restrict__ A2, u16* __restrict__ hb, int* __restrict__ flags,
    const u16* __restrict__ XP, float* __restrict__ out)
{
    const int wg = blockIdx.x, tid = threadIdx.x, lane = tid & 63, w = tid >> 6;
    const int mt = w & 1, nt2 = (w >> 1) & 1, ks = w >> 2;
    const int khi = lane >> 5, nb = nt2 * 32 + (lane & 31);

    __shared__ float GL[2 * 64 * 64];   // [ks][gate-row][batch]

    // A-fragments resident in VGPRs
    h16x8 afr[16];
    {
        const u32* ab = A2 + (size_t)((wg * 2 + mt) * 2 + ks) * (16 * 256) + lane * 4;
        #pragma unroll
        for (int kt = 0; kt < 16; ++kt) afr[kt] = *(const h16x8*)(ab + kt * 256);
    }

    const int bown = tid & 63, w8 = tid >> 6;
    const int j0 = wg * 16 + 2 * w8;
    float cst0, cst1;
    { f32x2 cv = *(const f32x2*)(c0 + bown * HH + j0); cst0 = cv.x; cst1 = cv.y; }

    // XP base for pointwise: grow = wg*64 + g*16 + (2*w8 + i)
    const u16* xp0 = XP + (size_t)(wg * 64 + 2 * w8) * TBN + bown;

    for (int t = 0; t < SS; ++t) {
        // XP prefetch (plain cached loads; issued before the spin)
        float xpv[8];
        #pragma unroll
        for (int g = 0; g < 4; ++g) {
            #pragma unroll
            for (int i = 0; i < 2; ++i)
                xpv[g * 2 + i] = h2f(xp0[(size_t)(g * 16 + i) * TBN + (size_t)t * BB]);
        }

        // wait for all WGs to have published h_t
        if (tid < NWG) { while (ld_i32_coh(&flags[tid]) < t) {} }
        asm volatile("" ::: "memory");
        __syncthreads();

        const u16* hsrc = hb + (t & 1) * (BB * HH);

        // issue ALL B-frag loads (coherent), then MFMA
        u32x4 bws[16];
        #pragma unroll
        for (int kt = 0; kt < 16; ++kt) {
            int k8 = ks * 32 + kt * 2 + khi;
            const u32* bp = (const u32*)(hsrc + k8 * 512 + nb * 8);
            bws[kt].x = ld_u32_coh(bp);
            bws[kt].y = ld_u32_coh(bp + 1);
            bws[kt].z = ld_u32_coh(bp + 2);
            bws[kt].w = ld_u32_coh(bp + 3);
        }
        f32x16 acc;
        #pragma unroll
        for (int rg = 0; rg < 16; ++rg) acc[rg] = 0.0f;
        #pragma unroll
        for (int kt = 0; kt < 16; ++kt) {
            union { u32x4 u; h16x8 h; } bc; bc.u = bws[kt];
            acc = __builtin_amdgcn_mfma_f32_32x32x16_f16(afr[kt], bc.h, acc, 0, 0, 0);
        }

        // gate exchange (disjoint plain LDS stores)
        #pragma unroll
        for (int rg = 0; rg < 16; ++rg) {
            int row = mt * 32 + (rg & 3) + 8 * (rg >> 2) + 4 * khi;
            GL[ks * 4096 + row * 64 + nb] = acc[rg];
        }
        __syncthreads();

        // pointwise for (bown, j0) and (bown, j0+1)
        const int m0 = 2 * w8, m1 = m0 + 1;
        float a0f = GL[(0 * 16 + m0) * 64 + bown] + GL[4096 + (0 * 16 + m0) * 64 + bown] + xpv[0];
        float a0i = GL[(1 * 16 + m0) * 64 + bown] + GL[4096 + (1 * 16 + m0) * 64 + bown] + xpv[2];
        float a0c = GL[(2 * 16 + m0) * 64 + bown] + GL[4096 + (2 * 16 + m0) * 64 + bown] + xpv[4];
        float a0o = GL[(3 * 16 + m0) * 64 + bown] + GL[4096 + (3 * 16 + m0) * 64 + bown] + xpv[6];
        float a1f = GL[(0 * 16 + m1) * 64 + bown] + GL[4096 + (0 * 16 + m1) * 64 + bown] + xpv[1];
        float a1i = GL[(1 * 16 + m1) * 64 + bown] + GL[4096 + (1 * 16 + m1) * 64 + bown] + xpv[3];
        float a1c = GL[(2 * 16 + m1) * 64 + bown] + GL[4096 + (2 * 16 + m1) * 64 + bown] + xpv[5];
        float a1o = GL[(3 * 16 + m1) * 64 + bown] + GL[4096 + (3 * 16 + m1) * 64 + bown] + xpv[7];

        float cn0 = cst0 * sigf(a0f) + sigf(a0i) * tanhf_(a0c); cst0 = cn0;
        float hv0 = sigf(a0o) * tanhf_(cn0);
        float cn1 = cst1 * sigf(a1f) + sigf(a1i) * tanhf_(a1c); cst1 = cn1;
        float hv1 = sigf(a1o) * tanhf_(cn1);

        // publish h_{t+1} (coherent u32: two adjacent f16)
        st_u32_coh((u32*)(hb + ((t + 1) & 1) * (BB * HH) + (j0 >> 3) * 512 + bown * 8 + (j0 & 7)),
                   pk2h(hv0, hv1));

        if (t < SS - 1) {
            __syncthreads();   // drains hb stores (vmcnt(0) before s_barrier)
            if (tid == 0) st_i32_coh(&flags[wg], t + 1);
        }

        // out store AFTER flag publish (off the critical path)
        f32x2 ho; ho.x = hv0; ho.y = hv1;
        *(f32x2*)(out + ((size_t)t * BB + bown) * HH + j0) = ho;
        if (t == SS - 1) {
            *(f32x2*)(out + (size_t)SS * BB * HH + bown * HH + j0) = ho;
            f32x2 co; co.x = cst0; co.y = cst1;
            *(f32x2*)(out + (size_t)SS * BB * HH + BB * HH + bown * HH + j0) = co;
        }
    }
}

// ===================================================================
// R5 fallback path (proven 2.63 ms) — verbatim
// ===================================================================
__global__ __launch_bounds__(256) void prep_A(
    const float* __restrict__ Wfi, const float* __restrict__ Wfh,
    const float* __restrict__ Wii, const float* __restrict__ Wih,
    const float* __restrict__ Wci, const float* __restrict__ Wch,
    const float* __restrict__ Woi, const float* __restrict__ Woh,
    u32* __restrict__ A)
{
    int tid = blockIdx.x * 256 + threadIdx.x;          // < 786432
    int wg = tid / 24576;  int r = tid - wg * 24576;
    int mt = r / 12288;    r -= mt * 12288;
    int ks = r / 6144;     r -= ks * 6144;
    int kt = r / 256;      r -= kt * 256;
    int l  = r >> 2;       int d = r & 3;

    int row = mt * 32 + (l & 31);
    int g   = row >> 4;
    int j   = wg * 16 + (row & 15);
    int k   = ks * 384 + kt * 16 + (l >> 5) * 8 + d * 2;

    const float* Wi = (g == 0) ? Wfi : (g == 1) ? Wii : (g == 2) ? Wci : Woi;
    const float* Wh = (g == 0) ? Wfh : (g == 1) ? Wih : (g == 2) ? Wch : Woh;
    float w0, w1;
    if (k < II) { w0 = Wi[j * II + k];        w1 = Wi[j * II + k + 1]; }
    else        { int kk = k - II; w0 = Wh[j * HH + kk]; w1 = Wh[j * HH + kk + 1]; }
    A[tid] = pk2h(w0, w1);
}

__global__ __launch_bounds__(256) void prep_misc(
    const float* __restrict__ h0, u16* __restrict__ hb, int* __restrict__ flags)
{
    int tid = blockIdx.x * 256 + threadIdx.x;          // < 32768
    if (tid < BB * HH) {
        int b = tid >> 9, j = tid & 511;
        hb[(j >> 3) * 512 + b * 8 + (j & 7)] = f2h(h0[tid]);
    }
    if (tid < NWG) flags[tid * 32] = 0;
}

__global__ __launch_bounds__(512, 1) void lstm_mfma(
    const float* __restrict__ x,  const float* __restrict__ c0,
    const float* __restrict__ bfi, const float* __restrict__ bfh,
    const float* __restrict__ bii, const float* __restrict__ bih,
    const float* __restrict__ bci, const float* __restrict__ bch,
    const float* __restrict__ boi, const float* __restrict__ boh,
    const u32* __restrict__ A, u16* __restrict__ hb, int* __restrict__ flags,
    float* __restrict__ out)
{
    const int wg   = blockIdx.x;
    const int tid  = threadIdx.x;
    const int lane = tid & 63;
    const int w    = tid >> 6;
    const int mt   = w & 1;
    const int nt2  = (w >> 1) & 1;
    const int ks   = w >> 2;
    const int khi  = lane >> 5;
    const int nb   = nt2 * 32 + (lane & 31);

    __shared__ __align__(16) u16 BS[8192 * 8];
    char* BSc = (char*)BS;

    h16x8 afr[24];
    {
        const u32* ab = A + ((wg * 2 + mt) * 2 + ks) * (24 * 256) + lane * 4;
        #pragma unroll
        for (int kt = 0; kt < 24; ++kt)
            afr[kt] = *(const h16x8*)(ab + kt * 256);
    }

    f32x16 acc_init;
    #pragma unroll
    for (int rg = 0; rg < 16; ++rg) {
        int row = mt * 32 + (rg & 3) + 8 * (rg >> 2) + 4 * khi;
        float bv = 0.0f;
        if (ks == 0) {
            int g = row >> 4, j = wg * 16 + (row & 15);
            const float* bi = (g == 0) ? bfi : (g == 1) ? bii : (g == 2) ? bci : boi;
            const float* bh = (g == 0) ? bfh : (g == 1) ? bih : (g == 2) ? bch : boh;
            bv = bi[j] + bh[j];
        }
        acc_init[rg] = bv;
    }

    const int bown = tid & 63;
    const int w8   = tid >> 6;
    const int j0   = wg * 16 + 2 * w8;
    float cst[2];
    {
        const f32x2 cv = *(const f32x2*)(c0 + bown * HH + j0);
        cst[0] = cv.x; cst[1] = cv.y;
    }

    #pragma unroll
    for (int i = 0; i < 4; ++i) {
        int cid = i * 512 + tid;
        int b = cid >> 5, k8 = cid & 31;
        const f32x4* sp = (const f32x4*)(x + b * II + k8 * 8);
        f32x4 v0 = sp[0], v1 = sp[1];
        u32x4 pk;
        pk.x = pk2h(v0[0], v0[1]); pk.y = pk2h(v0[2], v0[3]);
        pk.z = pk2h(v1[0], v1[1]); pk.w = pk2h(v1[2], v1[3]);
        *(u32x4*)&BSc[(k8 * 64 + (b ^ (k8 & 7))) * 16] = pk;
    }

    for (int t = 0; t < SS; ++t) {
        const int cur = t & 1;
        float* GLp = (float*)(BSc + (size_t)(cur ^ 1) * 2048 * 16);

        {
            const u16* hsrc = hb + cur * (BB * HH);
            u64 hr[16];
            #pragma unroll
            for (int it = 0; it < 8; ++it) {
                int cd = it * 512 + tid;
                int k8h = cd >> 6, bpos = cd & 63;
                int b = bpos ^ (k8h & 7);
                const u64* p = (const u64*)(hsrc + k8h * 512 + b * 8);
                hr[2 * it]     = ld_u64_coh(p);
                hr[2 * it + 1] = ld_u64_coh(p + 1);
            }
            #pragma unroll
            for (int it = 0; it < 8; ++it) {
                int cd = it * 512 + tid;
                union { u64 q[2]; u32x4 v; } u;
                u.q[0] = hr[2 * it]; u.q[1] = hr[2 * it + 1];
                *(u32x4*)&BSc[(4096 + cd) * 16] = u.v;
            }
        }

        f32x4 xv[8];
        if (t + 1 < SS) {
            const float* xt = x + (size_t)(t + 1) * BB * II;
            #pragma unroll
            for (int i = 0; i < 4; ++i) {
                int cid = i * 512 + tid;
                int b = cid >> 5, k8 = cid & 31;
                const f32x4* sp = (const f32x4*)(xt + b * II + k8 * 8);
                xv[2 * i] = sp[0]; xv[2 * i + 1] = sp[1];
            }
        }

        __syncthreads();

        f32x16 acc = acc_init;
        #pragma unroll
        for (int kt = 0; kt < 24; ++kt) {
            int k8g = ks * 48 + kt * 2 + khi;
            int off;
            if (k8g < 32) { int q = k8g & 7;
                off = (cur * 2048 + k8g * 64 + ((nb ^ q))) * 16;
            } else {        int k8h = k8g - 32; int q = k8h & 7;
                off = (4096 + k8h * 64 + ((nb ^ q))) * 16;
            }
            h16x8 bf = *(const h16x8*)(BSc + off);
            acc = __builtin_amdgcn_mfma_f32_32x32x16_f16(afr[kt], bf, acc, 0, 0, 0);
        }

        #pragma unroll
        for (int rg = 0; rg < 16; ++rg) {
            int row = mt * 32 + (rg & 3) + 8 * (rg >> 2) + 4 * khi;
            GLp[ks * 4096 + row * 64 + nb] = acc[rg];
        }
        __syncthreads();

        float hv2[2];
        #pragma unroll
        for (int i = 0; i < 2; ++i) {
            int m = 2 * w8 + i;
            float af = GLp[(0 * 16 + m) * 64 + bown] + GLp[4096 + (0 * 16 + m) * 64 + bown];
            float ai = GLp[(1 * 16 + m) * 64 + bown] + GLp[4096 + (1 * 16 + m) * 64 + bown];
            float ac = GLp[(2 * 16 + m) * 64 + bown] + GLp[4096 + (2 * 16 + m) * 64 + bown];
            float ao = GLp[(3 * 16 + m) * 64 + bown] + GLp[4096 + (3 * 16 + m) * 64 + bown];
            float fg = sigf(af), ig = sigf(ai), cg = tanhf_(ac), og = sigf(ao);
            float cn = cst[i] * fg + ig * cg;
            cst[i] = cn;
            hv2[i] = og * tanhf_(cn);
        }
        {
            f32x2 ho; ho.x = hv2[0]; ho.y = hv2[1];
            *(f32x2*)(out + ((size_t)t * BB + bown) * HH + j0) = ho;
        }
        st_u32_coh((u32*)(hb + ((t + 1) & 1) * (BB * HH) + (j0 >> 3) * 512 + bown * 8 + (j0 & 7)),
                   pk2h(hv2[0], hv2[1]));

        if (t == SS - 1) {
            f32x2 ho; ho.x = hv2[0]; ho.y = hv2[1];
            f32x2 co; co.x = cst[0]; co.y = cst[1];
            *(f32x2*)(out + (size_t)SS * BB * HH + bown * HH + j0) = ho;
            *(f32x2*)(out + (size_t)SS * BB * HH + BB * HH + bown * HH + j0) = co;
            break;
        }

        __syncthreads();
        if (tid == 0) st_i32_coh(&flags[wg * 32], t + 1);

        #pragma unroll
        for (int i = 0; i < 4; ++i) {
            int cid = i * 512 + tid;
            int b = cid >> 5, k8 = cid & 31;
            f32x4 v0 = xv[2 * i], v1 = xv[2 * i + 1];
            u32x4 pk;
            pk.x = pk2h(v0[0], v0[1]); pk.y = pk2h(v0[2], v0[3]);
            pk.z = pk2h(v1[0], v1[1]); pk.w = pk2h(v1[2], v1[3]);
            *(u32x4*)&BSc[((cur ^ 1) * 2048 + k8 * 64 + (b ^ (k8 & 7))) * 16] = pk;
        }

        if (tid < NWG) {
            while (ld_i32_coh(&flags[tid * 32]) < t + 1) {}
        }
        asm volatile("" ::: "memory");
        __syncthreads();
    }
}

extern "C" void kernel_launch(void* const* d_in, const int* in_sizes, int n_in,
                              void* d_out, int out_size, void* d_ws, size_t ws_size,
                              hipStream_t stream) {
    const float* x   = (const float*)d_in[0];
    const float* h0  = (const float*)d_in[1];
    const float* c0  = (const float*)d_in[2];
    const float* Wfi = (const float*)d_in[3];
    const float* bfi = (const float*)d_in[4];
    const float* Wfh = (const float*)d_in[5];
    const float* bfh = (const float*)d_in[6];
    const float* Wii = (const float*)d_in[7];
    const float* bii = (const float*)d_in[8];
    const float* Wih = (const float*)d_in[9];
    const float* bih = (const float*)d_in[10];
    const float* Wci = (const float*)d_in[11];
    const float* bci = (const float*)d_in[12];
    const float* Wch = (const float*)d_in[13];
    const float* bch = (const float*)d_in[14];
    const float* Woi = (const float*)d_in[15];
    const float* boi = (const float*)d_in[16];
    const float* Woh = (const float*)d_in[17];
    const float* boh = (const float*)d_in[18];

    if (ws_size >= WS_XP) {
        u32*   A2   = (u32*)((char*)d_ws + XA2_OFF);
        u32*   WXA  = (u32*)((char*)d_ws + XWXA_OFF);
        float* bsum = (float*)((char*)d_ws + XBS_OFF);
        u16*   hbb  = (u16*)((char*)d_ws + XHB_OFF);
        int*   flg  = (int*)((char*)d_ws + XFL_OFF);
        u16*   XP   = (u16*)((char*)d_ws + XXP_OFF);

        xprep_pack<<<dim3((A2_DW + WXA_DW + GROW) / 256), dim3(256), 0, stream>>>(
            Wfi, Wfh, Wii, Wih, Wci, Wch, Woi, Woh,
            bfi, bfh, bii, bih, bci, bch, boi, boh, A2, WXA, bsum);
        xprep_hb<<<dim3(128), dim3(256), 0, stream>>>(h0, hbb, flg);
        xproj<<<dim3(TBN / 128), dim3(512), 0, stream>>>(x, WXA, bsum, XP);
        lstm_rec<<<dim3(NWG), dim3(512), 0, stream>>>(c0, A2, hbb, flg, XP, (float*)d_out);
    } else {
        u32* A     = (u32*)d_ws;
        u16* hbb   = (u16*)((char*)d_ws + HB_OFF);
        int* flags = (int*)((char*)d_ws + FL_OFF);
        prep_A<<<dim3(A_DWORDS / 256), dim3(256), 0, stream>>>(
            Wfi, Wfh, Wii, Wih, Wci, Wch, Woi, Woh, A);
        prep_misc<<<dim3(128), dim3(256), 0, stream>>>(h0, hbb, flags);
        lstm_mfma<<<dim3(NWG), dim3(512), 0, stream>>>(
            x, c0, bfi, bfh, bii, bih, bci, bch, boi, boh,
            A, hbb, flags, (float*)d_out);
    }
}

// Round 7
// 2640.262 us; speedup vs baseline: 1.7671x; 1.7671x over previous
//
#include <hip/hip_runtime.h>

// LSTM S=512,B=64,I=256,H=512 (f32 buffers).
// R7: R6 regressed (4.67ms) from 4x-amplified dword-atomic B-frag loads
// (512KB/WG/step coherent traffic @ ~57GB/s per-CU port = 9us/step).
// Fix: 16 WGs, gate-interleaved rows (row=m*4+g), each wave = 32x32 tile,
// FULL K=512 (32 MFMAs, A resident in 128 VGPRs) -> pointwise fully
// in-register (no GL exchange). h restage: consecutive-lane u64 coherent
// loads (zero amplification, 64KB/WG/step) -> LDS -> ds_read_b128 frags.
// XP precomputed as [j][t][b][4 gates] u64 (one load per lane per unit).
// Publish: 4KB LDS gather -> 512 coalesced u64 coherent stores.
// Sync: R5's proven fence-free relaxed agent-scope protocol.

#define SS 512
#define BB 64
#define II 256
#define HH 512
#define NWG 16
#define GROW 2048
#define TBN  (SS*BB)

typedef unsigned int u32;
typedef unsigned short u16;
typedef unsigned long long u64;
typedef _Float16 __attribute__((ext_vector_type(8))) h16x8;
typedef __attribute__((ext_vector_type(2))) float f32x2;
typedef __attribute__((ext_vector_type(4))) float f32x4;
typedef __attribute__((ext_vector_type(16))) float f32x16;
typedef u32 __attribute__((ext_vector_type(4))) u32x4;
typedef u32 __attribute__((ext_vector_type(2))) u32x2;

// ---------------- XP-path ws layout ----------------
#define A2_DW   (NWG * 4 * 32 * 256)          // 524288 dwords = 2 MB (h A-frags)
#define WXA_DW  (64 * 16 * 256)               // 262144 dwords = 1 MB (x A-frags)
#define XA2_OFF  0
#define XWXA_OFF ((size_t)A2_DW * 4)                    // 2,097,152
#define XBS_OFF  (XWXA_OFF + (size_t)WXA_DW * 4)        // 3,145,728 (bsum 8 KB)
#define XHB_OFF  (XBS_OFF + 8192)                       // 3,153,920 (hb 128 KB)
#define XFL_OFF  (XHB_OFF + 2 * (size_t)BB * HH * 2)    // 3,284,992 (flags)
#define XXP_OFF  ((size_t)4 * 1024 * 1024)              // 4,194,304
#define XP_BYTES ((size_t)GROW * TBN * 2)               // 134,217,728
#define WS_XP    (XXP_OFF + XP_BYTES)                   // 138,412,032

// ---------------- R5-fallback ws layout ----------------
#define A_DWORDS (32 * 2 * 2 * 24 * 64 * 4)           // 786432
#define HB_OFF   ((size_t)A_DWORDS * 4)               // 3,145,728
#define FL_OFF   (HB_OFF + 2 * (size_t)BB * HH * 2)   // +131,072
#define WS_NEED  (FL_OFF + 4096)

__device__ __forceinline__ u32 pk2h(float a, float b) {
    union { _Float16 h[2]; u32 u; } v;
    v.h[0] = (_Float16)a; v.h[1] = (_Float16)b; return v.u;
}
__device__ __forceinline__ u16 f2h(float a) {
    union { _Float16 h; u16 u; } v; v.h = (_Float16)a; return v.u;
}
__device__ __forceinline__ float h2f(u16 u) {
    union { u16 u; _Float16 h; } v; v.u = u; return (float)v.h;
}
__device__ __forceinline__ float sigf(float v)  { return 1.0f / (1.0f + __expf(-v)); }
__device__ __forceinline__ float tanhf_(float v){ return 1.0f - 2.0f / (1.0f + __expf(2.0f * v)); }

// relaxed agent-scope (coherent-at-L3, no cache-maintenance fences)
__device__ __forceinline__ void st_u32_coh(u32* p, u32 v) {
    __hip_atomic_store(p, v, __ATOMIC_RELAXED, __HIP_MEMORY_SCOPE_AGENT);
}
__device__ __forceinline__ void st_u64_coh(u64* p, u64 v) {
    __hip_atomic_store(p, v, __ATOMIC_RELAXED, __HIP_MEMORY_SCOPE_AGENT);
}
__device__ __forceinline__ void st_i32_coh(int* p, int v) {
    __hip_atomic_store(p, v, __ATOMIC_RELAXED, __HIP_MEMORY_SCOPE_AGENT);
}
__device__ __forceinline__ int ld_i32_coh(const int* p) {
    return __hip_atomic_load(p, __ATOMIC_RELAXED, __HIP_MEMORY_SCOPE_AGENT);
}
__device__ __forceinline__ u64 ld_u64_coh(const u64* p) {
    return __hip_atomic_load(p, __ATOMIC_RELAXED, __HIP_MEMORY_SCOPE_AGENT);
}

// ===================================================================
// XP path (R7)
// ===================================================================

// A2: h-weight A-frags. idx = ((wg*4+mt)*32+kt)*256 + l*4 + d.
//   r=l&31: g=r&3, ml=r>>2; j=wg*32+mt*8+ml; k=kt*16+(l>>5)*8+d*2.
// WXA: x-weight A-frags for xproj. idx = (gt*16+kt)*256 + l*4 + d.
//   r=l&31: j=gt*8+(r>>2), g=r&3; k=kt*16+(l>>5)*8+d*2.
// bsum[grow]: grow = gt*32 + r (same row mapping as xproj tiles).
__global__ __launch_bounds__(256) void xprep_pack(
    const float* __restrict__ Wfi, const float* __restrict__ Wfh,
    const float* __restrict__ Wii, const float* __restrict__ Wih,
    const float* __restrict__ Wci, const float* __restrict__ Wch,
    const float* __restrict__ Woi, const float* __restrict__ Woh,
    const float* __restrict__ bfi, const float* __restrict__ bfh,
    const float* __restrict__ bii, const float* __restrict__ bih,
    const float* __restrict__ bci, const float* __restrict__ bch,
    const float* __restrict__ boi, const float* __restrict__ boh,
    u32* __restrict__ A2, u32* __restrict__ WXA, float* __restrict__ bsum)
{
    int tid = blockIdx.x * 256 + threadIdx.x;
    if (tid < A2_DW) {
        int d = tid & 3, l = (tid >> 2) & 63, kt = (tid >> 8) & 31;
        int mt = (tid >> 13) & 3, wg = tid >> 15;
        int r = l & 31, g = r & 3, ml = r >> 2;
        int j = wg * 32 + mt * 8 + ml;
        int k = kt * 16 + (l >> 5) * 8 + d * 2;
        const float* Wh = (g == 0) ? Wfh : (g == 1) ? Wih : (g == 2) ? Wch : Woh;
        A2[tid] = pk2h(Wh[j * HH + k], Wh[j * HH + k + 1]);
    } else if (tid < A2_DW + WXA_DW) {
        int t2 = tid - A2_DW;
        int d = t2 & 3, l = (t2 >> 2) & 63, kt = (t2 >> 8) & 15, gt = t2 >> 12;
        int r = l & 31, g = r & 3;
        int j = gt * 8 + (r >> 2);
        int k = kt * 16 + (l >> 5) * 8 + d * 2;
        const float* Wi = (g == 0) ? Wfi : (g == 1) ? Wii : (g == 2) ? Wci : Woi;
        WXA[t2] = pk2h(Wi[j * II + k], Wi[j * II + k + 1]);
    } else if (tid < A2_DW + WXA_DW + GROW) {
        int grow = tid - A2_DW - WXA_DW;     // = gt*32 + r
        int r = grow & 31, gt = grow >> 5;
        int g = r & 3, j = gt * 8 + (r >> 2);
        const float* bi = (g == 0) ? bfi : (g == 1) ? bii : (g == 2) ? bci : boi;
        const float* bh = (g == 0) ? bfh : (g == 1) ? bih : (g == 2) ? bch : boh;
        bsum[grow] = bi[j] + bh[j];
    }
}

__global__ __launch_bounds__(256) void xprep_hb(
    const float* __restrict__ h0, u16* __restrict__ hb, int* __restrict__ flags)
{
    int tid = blockIdx.x * 256 + threadIdx.x;   // < 32768
    if (tid < BB * HH) {
        int b = tid >> 9, j = tid & 511;
        hb[(j >> 3) * 512 + b * 8 + (j & 7)] = f2h(h0[tid]);
    }
    if (tid < NWG) flags[tid] = 0;
}

// xproj: XPq[(j*512 + t)*64 + b] = u64 of 4 f16 gates {f,i,c,o} of unit j,
// = x_t[b] @ Wxi[g][j,:] + (bi+bh). 256 WGs x 128 tb-rows.
__global__ __launch_bounds__(512, 1) void xproj(
    const float* __restrict__ x, const u32* __restrict__ WXA,
    const float* __restrict__ bsum, u64* __restrict__ XPq)
{
    const int wgid = blockIdx.x;
    const int tid = threadIdx.x, lane = tid & 63, w = tid >> 6;
    const int TB0 = wgid * 128;
    __shared__ __align__(16) u32 XB[32 * 128 * 4];   // [k8][tbl] 16B entries

    // stage x-tile (128 tb x 256 k) f32 -> f16 packed
    #pragma unroll
    for (int it = 0; it < 16; ++it) {
        int c = it * 512 + tid;
        int m = c >> 6, ck = c & 63;
        f32x4 v = *(const f32x4*)(x + (size_t)(TB0 + m) * II + ck * 4);
        u32x2 p; p.x = pk2h(v.x, v.y); p.y = pk2h(v.z, v.w);
        *(u32x2*)(XB + ((ck >> 1) * 128 + m) * 4 + (ck & 1) * 2) = p;
    }
    __syncthreads();

    const int gtw = w & 3, nh = w >> 2;
    const int khi = lane >> 5;
    for (int nt = 0; nt < 2; ++nt) {
        const int col = nh * 64 + nt * 32 + (lane & 31);   // tb-local
        const int tb = TB0 + col;
        const int t_ = tb >> 6, b_ = tb & 63;
        h16x8 bfr[16];
        #pragma unroll
        for (int kt = 0; kt < 16; ++kt)
            bfr[kt] = *(const h16x8*)(XB + ((kt * 2 + khi) * 128 + col) * 4);
        for (int gti = 0; gti < 16; ++gti) {
            const int gt = gtw * 16 + gti;
            f32x16 acc;
            #pragma unroll
            for (int rg = 0; rg < 16; ++rg)
                acc[rg] = bsum[gt * 32 + (rg & 3) + 8 * (rg >> 2) + 4 * khi];
            const u32* ap = WXA + (size_t)(gt * 16) * 256 + lane * 4;
            #pragma unroll
            for (int kt = 0; kt < 16; ++kt) {
                h16x8 af = *(const h16x8*)(ap + kt * 256);
                acc = __builtin_amdgcn_mfma_f32_32x32x16_f16(af, bfr[kt], acc, 0, 0, 0);
            }
            #pragma unroll
            for (int q = 0; q < 4; ++q) {
                int j = gt * 8 + 2 * q + khi;
                union { u16 s[4]; u64 u; } pk;
                pk.s[0] = f2h(acc[4 * q + 0]);
                pk.s[1] = f2h(acc[4 * q + 1]);
                pk.s[2] = f2h(acc[4 * q + 2]);
                pk.s[3] = f2h(acc[4 * q + 3]);
                XPq[((size_t)j * 512 + t_) * 64 + b_] = pk.u;
            }
        }
    }
}

// recurrent: 16 WGs x 8 waves (mt 0..3, nt2 0..1), full-K per wave,
// in-register pointwise, LDS h-stage, coalesced coherent traffic only.
__global__ __launch_bounds__(512, 2) void lstm_rec(
    const float* __restrict__ c0,
    const u32* __restrict__ A2, u16* __restrict__ hb, int* __restrict__ flags,
    const u64* __restrict__ XPq, float* __restrict__ out)
{
    const int wg = blockIdx.x, tid = threadIdx.x, lane = tid & 63, w = tid >> 6;
    const int mt = w & 3, nt2 = w >> 2;
    const int khi = lane >> 5;
    const int b = nt2 * 32 + (lane & 31);

    __shared__ u64 HL[8192];        // 64 KB: mirror of hb[cur], [k8][b][e8]
    __shared__ u16 hst[2048];       // 4 KB publish stage: [mt][b][e8]

    u64* hb64 = (u64*)hb;

    // A-fragments resident in VGPRs (32 x 16B = 128 VGPRs)
    h16x8 afr[32];
    {
        const u32* ab = A2 + (size_t)(wg * 4 + mt) * (32 * 256) + lane * 4;
        #pragma unroll
        for (int kt = 0; kt < 32; ++kt) afr[kt] = *(const h16x8*)(ab + kt * 256);
    }

    // c-state: lane owns batch b, units j = wg*32 + mt*8 + 2q + khi, q=0..3
    float cst[4];
    #pragma unroll
    for (int q = 0; q < 4; ++q)
        cst[q] = c0[b * HH + wg * 32 + mt * 8 + 2 * q + khi];

    const u16* HLu = (const u16*)HL;

    for (int t = 0; t < SS; ++t) {
        // XP prefetch: one u64 (4 gates) per unit, coalesced plain loads
        u64 xq[4];
        #pragma unroll
        for (int q = 0; q < 4; ++q) {
            int j = wg * 32 + mt * 8 + 2 * q + khi;
            xq[q] = XPq[((size_t)j * 512 + t) * 64 + b];
        }

        // wait for all WGs to have published h_t
        if (tid < NWG) { while (ld_i32_coh(&flags[tid]) < t) {} }
        asm volatile("" ::: "memory");
        __syncthreads();

        // h restage: consecutive lanes -> consecutive u64 (zero amplification)
        {
            const u64* hsrc = hb64 + (size_t)(t & 1) * 8192;
            u64 hv8[8];
            #pragma unroll
            for (int i = 0; i < 8; ++i) hv8[i] = ld_u64_coh(hsrc + i * 512 + tid);
            #pragma unroll
            for (int i = 0; i < 8; ++i) HL[i * 512 + tid] = hv8[i];
            #pragma unroll
            for (int i = 0; i < 8; ++i) hv8[i] = ld_u64_coh(hsrc + (i + 8) * 512 + tid);
            #pragma unroll
            for (int i = 0; i < 8; ++i) HL[(i + 8) * 512 + tid] = hv8[i];
        }
        __syncthreads();

        // K-loop: 32 MFMAs, full K=512, B-frags via ds_read_b128
        f32x16 acc;
        #pragma unroll
        for (int rg = 0; rg < 16; ++rg) acc[rg] = 0.0f;
        #pragma unroll
        for (int kt = 0; kt < 32; ++kt) {
            const int k8 = kt * 2 + khi;
            h16x8 bf = *(const h16x8*)(HLu + (k8 * 64 + b) * 8);
            acc = __builtin_amdgcn_mfma_f32_32x32x16_f16(afr[kt], bf, acc, 0, 0, 0);
        }

        // in-register pointwise: lane has all 4 gates for its 4 units
        float hvv[4];
        #pragma unroll
        for (int q = 0; q < 4; ++q) {
            union { u64 u; u16 s[4]; } xu; xu.u = xq[q];
            float af = acc[4 * q + 0] + h2f(xu.s[0]);
            float ai = acc[4 * q + 1] + h2f(xu.s[1]);
            float ac = acc[4 * q + 2] + h2f(xu.s[2]);
            float ao = acc[4 * q + 3] + h2f(xu.s[3]);
            float cn = cst[q] * sigf(af) + sigf(ai) * tanhf_(ac);
            cst[q] = cn;
            float hv = sigf(ao) * tanhf_(cn);
            hvv[q] = hv;
            hst[mt * 512 + b * 8 + 2 * q + khi] = f2h(hv);
        }

        if (t < SS - 1) {
            __syncthreads();   // hst complete
            // publish: 512 consecutive u64 coherent stores (fully coalesced)
            u64 pk = *(const u64*)(hst + tid * 4);
            st_u64_coh(hb64 + (size_t)((t + 1) & 1) * 8192 + wg * 512 + tid, pk);
            __syncthreads();   // drain (vmcnt 0) before flag
            if (tid == 0) st_i32_coh(&flags[wg], t + 1);
        }

        // out stores after flag publish (acks overlap next spin)
        #pragma unroll
        for (int q = 0; q < 4; ++q) {
            int j = wg * 32 + mt * 8 + 2 * q + khi;
            out[((size_t)t * BB + b) * HH + j] = hvv[q];
        }
        if (t == SS - 1) {
            #pragma unroll
            for (int q = 0; q < 4; ++q) {
                int j = wg * 32 + mt * 8 + 2 * q + khi;
                out[(size_t)SS * BB * HH + b * HH + j] = hvv[q];
                out[(size_t)SS * BB * HH + BB * HH + b * HH + j] = cst[q];
            }
        }
    }
}

// ===================================================================
// R5 fallback path (proven 2.63 ms) — verbatim
// ===================================================================
__global__ __launch_bounds__(256) void prep_A(
    const float* __restrict__ Wfi, const float* __restrict__ Wfh,
    const float* __restrict__ Wii, const float* __restrict__ Wih,
    const float* __restrict__ Wci, const float* __restrict__ Wch,
    const float* __restrict__ Woi, const float* __restrict__ Woh,
    u32* __restrict__ A)
{
    int tid = blockIdx.x * 256 + threadIdx.x;          // < 786432
    int wg = tid / 24576;  int r = tid - wg * 24576;
    int mt = r / 12288;    r -= mt * 12288;
    int ks = r / 6144;     r -= ks * 6144;
    int kt = r / 256;      r -= kt * 256;
    int l  = r >> 2;       int d = r & 3;

    int row = mt * 32 + (l & 31);
    int g   = row >> 4;
    int j   = wg * 16 + (row & 15);
    int k   = ks * 384 + kt * 16 + (l >> 5) * 8 + d * 2;

    const float* Wi = (g == 0) ? Wfi : (g == 1) ? Wii : (g == 2) ? Wci : Woi;
    const float* Wh = (g == 0) ? Wfh : (g == 1) ? Wih : (g == 2) ? Wch : Woh;
    float w0, w1;
    if (k < II) { w0 = Wi[j * II + k];        w1 = Wi[j * II + k + 1]; }
    else        { int kk = k - II; w0 = Wh[j * HH + kk]; w1 = Wh[j * HH + kk + 1]; }
    A[tid] = pk2h(w0, w1);
}

__global__ __launch_bounds__(256) void prep_misc(
    const float* __restrict__ h0, u16* __restrict__ hb, int* __restrict__ flags)
{
    int tid = blockIdx.x * 256 + threadIdx.x;          // < 32768
    if (tid < BB * HH) {
        int b = tid >> 9, j = tid & 511;
        hb[(j >> 3) * 512 + b * 8 + (j & 7)] = f2h(h0[tid]);
    }
    if (tid < 32) flags[tid * 32] = 0;
}

__global__ __launch_bounds__(512, 1) void lstm_mfma(
    const float* __restrict__ x,  const float* __restrict__ c0,
    const float* __restrict__ bfi, const float* __restrict__ bfh,
    const float* __restrict__ bii, const float* __restrict__ bih,
    const float* __restrict__ bci, const float* __restrict__ bch,
    const float* __restrict__ boi, const float* __restrict__ boh,
    const u32* __restrict__ A, u16* __restrict__ hb, int* __restrict__ flags,
    float* __restrict__ out)
{
    const int wg   = blockIdx.x;
    const int tid  = threadIdx.x;
    const int lane = tid & 63;
    const int w    = tid >> 6;
    const int mt   = w & 1;
    const int nt2  = (w >> 1) & 1;
    const int ks   = w >> 2;
    const int khi  = lane >> 5;
    const int nb   = nt2 * 32 + (lane & 31);

    __shared__ __align__(16) u16 BS[8192 * 8];
    char* BSc = (char*)BS;

    h16x8 afr[24];
    {
        const u32* ab = A + ((wg * 2 + mt) * 2 + ks) * (24 * 256) + lane * 4;
        #pragma unroll
        for (int kt = 0; kt < 24; ++kt)
            afr[kt] = *(const h16x8*)(ab + kt * 256);
    }

    f32x16 acc_init;
    #pragma unroll
    for (int rg = 0; rg < 16; ++rg) {
        int row = mt * 32 + (rg & 3) + 8 * (rg >> 2) + 4 * khi;
        float bv = 0.0f;
        if (ks == 0) {
            int g = row >> 4, j = wg * 16 + (row & 15);
            const float* bi = (g == 0) ? bfi : (g == 1) ? bii : (g == 2) ? bci : boi;
            const float* bh = (g == 0) ? bfh : (g == 1) ? bih : (g == 2) ? bch : boh;
            bv = bi[j] + bh[j];
        }
        acc_init[rg] = bv;
    }

    const int bown = tid & 63;
    const int w8   = tid >> 6;
    const int j0   = wg * 16 + 2 * w8;
    float cst[2];
    {
        const f32x2 cv = *(const f32x2*)(c0 + bown * HH + j0);
        cst[0] = cv.x; cst[1] = cv.y;
    }

    #pragma unroll
    for (int i = 0; i < 4; ++i) {
        int cid = i * 512 + tid;
        int bq = cid >> 5, k8 = cid & 31;
        const f32x4* sp = (const f32x4*)(x + bq * II + k8 * 8);
        f32x4 v0 = sp[0], v1 = sp[1];
        u32x4 pk;
        pk.x = pk2h(v0[0], v0[1]); pk.y = pk2h(v0[2], v0[3]);
        pk.z = pk2h(v1[0], v1[1]); pk.w = pk2h(v1[2], v1[3]);
        *(u32x4*)&BSc[(k8 * 64 + (bq ^ (k8 & 7))) * 16] = pk;
    }

    for (int t = 0; t < SS; ++t) {
        const int cur = t & 1;
        float* GLp = (float*)(BSc + (size_t)(cur ^ 1) * 2048 * 16);

        {
            const u16* hsrc = hb + cur * (BB * HH);
            u64 hr[16];
            #pragma unroll
            for (int it = 0; it < 8; ++it) {
                int cd = it * 512 + tid;
                int k8h = cd >> 6, bpos = cd & 63;
                int bq = bpos ^ (k8h & 7);
                const u64* p = (const u64*)(hsrc + k8h * 512 + bq * 8);
                hr[2 * it]     = ld_u64_coh(p);
                hr[2 * it + 1] = ld_u64_coh(p + 1);
            }
            #pragma unroll
            for (int it = 0; it < 8; ++it) {
                int cd = it * 512 + tid;
                union { u64 q[2]; u32x4 v; } u;
                u.q[0] = hr[2 * it]; u.q[1] = hr[2 * it + 1];
                *(u32x4*)&BSc[(4096 + cd) * 16] = u.v;
            }
        }

        f32x4 xv[8];
        if (t + 1 < SS) {
            const float* xt = x + (size_t)(t + 1) * BB * II;
            #pragma unroll
            for (int i = 0; i < 4; ++i) {
                int cid = i * 512 + tid;
                int bq = cid >> 5, k8 = cid & 31;
                const f32x4* sp = (const f32x4*)(xt + bq * II + k8 * 8);
                xv[2 * i] = sp[0]; xv[2 * i + 1] = sp[1];
            }
        }

        __syncthreads();

        f32x16 acc = acc_init;
        #pragma unroll
        for (int kt = 0; kt < 24; ++kt) {
            int k8g = ks * 48 + kt * 2 + khi;
            int off;
            if (k8g < 32) { int q = k8g & 7;
                off = (cur * 2048 + k8g * 64 + ((nb ^ q))) * 16;
            } else {        int k8h = k8g - 32; int q = k8h & 7;
                off = (4096 + k8h * 64 + ((nb ^ q))) * 16;
            }
            h16x8 bf = *(const h16x8*)(BSc + off);
            acc = __builtin_amdgcn_mfma_f32_32x32x16_f16(afr[kt], bf, acc, 0, 0, 0);
        }

        #pragma unroll
        for (int rg = 0; rg < 16; ++rg) {
            int row = mt * 32 + (rg & 3) + 8 * (rg >> 2) + 4 * khi;
            GLp[ks * 4096 + row * 64 + nb] = acc[rg];
        }
        __syncthreads();

        float hv2[2];
        #pragma unroll
        for (int i = 0; i < 2; ++i) {
            int m = 2 * w8 + i;
            float af = GLp[(0 * 16 + m) * 64 + bown] + GLp[4096 + (0 * 16 + m) * 64 + bown];
            float ai = GLp[(1 * 16 + m) * 64 + bown] + GLp[4096 + (1 * 16 + m) * 64 + bown];
            float ac = GLp[(2 * 16 + m) * 64 + bown] + GLp[4096 + (2 * 16 + m) * 64 + bown];
            float ao = GLp[(3 * 16 + m) * 64 + bown] + GLp[4096 + (3 * 16 + m) * 64 + bown];
            float fg = sigf(af), ig = sigf(ai), cg = tanhf_(ac), og = sigf(ao);
            float cn = cst[i] * fg + ig * cg;
            cst[i] = cn;
            hv2[i] = og * tanhf_(cn);
        }
        {
            f32x2 ho; ho.x = hv2[0]; ho.y = hv2[1];
            *(f32x2*)(out + ((size_t)t * BB + bown) * HH + j0) = ho;
        }
        st_u32_coh((u32*)(hb + ((t + 1) & 1) * (BB * HH) + (j0 >> 3) * 512 + bown * 8 + (j0 & 7)),
                   pk2h(hv2[0], hv2[1]));

        if (t == SS - 1) {
            f32x2 ho; ho.x = hv2[0]; ho.y = hv2[1];
            f32x2 co; co.x = cst[0]; co.y = cst[1];
            *(f32x2*)(out + (size_t)SS * BB * HH + bown * HH + j0) = ho;
            *(f32x2*)(out + (size_t)SS * BB * HH + BB * HH + bown * HH + j0) = co;
            break;
        }

        __syncthreads();
        if (tid == 0) st_i32_coh(&flags[wg * 32], t + 1);

        #pragma unroll
        for (int i = 0; i < 4; ++i) {
            int cid = i * 512 + tid;
            int bq = cid >> 5, k8 = cid & 31;
            f32x4 v0 = xv[2 * i], v1 = xv[2 * i + 1];
            u32x4 pk;
            pk.x = pk2h(v0[0], v0[1]); pk.y = pk2h(v0[2], v0[3]);
            pk.z = pk2h(v1[0], v1[1]); pk.w = pk2h(v1[2], v1[3]);
            *(u32x4*)&BSc[((cur ^ 1) * 2048 + k8 * 64 + (bq ^ (k8 & 7))) * 16] = pk;
        }

        if (tid < 32) {
            while (ld_i32_coh(&flags[tid * 32]) < t + 1) {}
        }
        asm volatile("" ::: "memory");
        __syncthreads();
    }
}

extern "C" void kernel_launch(void* const* d_in, const int* in_sizes, int n_in,
                              void* d_out, int out_size, void* d_ws, size_t ws_size,
                              hipStream_t stream) {
    const float* x   = (const float*)d_in[0];
    const float* h0  = (const float*)d_in[1];
    const float* c0  = (const float*)d_in[2];
    const float* Wfi = (const float*)d_in[3];
    const float* bfi = (const float*)d_in[4];
    const float* Wfh = (const float*)d_in[5];
    const float* bfh = (const float*)d_in[6];
    const float* Wii = (const float*)d_in[7];
    const float* bii = (const float*)d_in[8];
    const float* Wih = (const float*)d_in[9];
    const float* bih = (const float*)d_in[10];
    const float* Wci = (const float*)d_in[11];
    const float* bci = (const float*)d_in[12];
    const float* Wch = (const float*)d_in[13];
    const float* bch = (const float*)d_in[14];
    const float* Woi = (const float*)d_in[15];
    const float* boi = (const float*)d_in[16];
    const float* Woh = (const float*)d_in[17];
    const float* boh = (const float*)d_in[18];

    if (ws_size >= WS_XP) {
        u32*   A2   = (u32*)((char*)d_ws + XA2_OFF);
        u32*   WXA  = (u32*)((char*)d_ws + XWXA_OFF);
        float* bsum = (float*)((char*)d_ws + XBS_OFF);
        u16*   hbb  = (u16*)((char*)d_ws + XHB_OFF);
        int*   flg  = (int*)((char*)d_ws + XFL_OFF);
        u64*   XPq  = (u64*)((char*)d_ws + XXP_OFF);

        xprep_pack<<<dim3((A2_DW + WXA_DW + GROW + 255) / 256), dim3(256), 0, stream>>>(
            Wfi, Wfh, Wii, Wih, Wci, Wch, Woi, Woh,
            bfi, bfh, bii, bih, bci, bch, boi, boh, A2, WXA, bsum);
        xprep_hb<<<dim3(128), dim3(256), 0, stream>>>(h0, hbb, flg);
        xproj<<<dim3(TBN / 128), dim3(512), 0, stream>>>(x, WXA, bsum, XPq);
        lstm_rec<<<dim3(NWG), dim3(512), 0, stream>>>(c0, A2, hbb, flg, XPq, (float*)d_out);
    } else {
        u32* A     = (u32*)d_ws;
        u16* hbb   = (u16*)((char*)d_ws + HB_OFF);
        int* flags = (int*)((char*)d_ws + FL_OFF);
        prep_A<<<dim3(A_DWORDS / 256), dim3(256), 0, stream>>>(
            Wfi, Wfh, Wii, Wih, Wci, Wch, Woi, Woh, A);
        prep_misc<<<dim3(128), dim3(256), 0, stream>>>(h0, hbb, flags);
        lstm_mfma<<<dim3(32), dim3(512), 0, stream>>>(
            x, c0, bfi, bfh, bii, bih, bci, bch, boi, boh,
            A, hbb, flags, (float*)d_out);
    }
}